// Round 11
// baseline (870.299 us; speedup 1.0000x reference)
//
#include <hip/hip_runtime.h>
#include <math.h>
#include <stdint.h>

#define NB 512
#define NI 8192
#define NG (NI / 4)   // 2048 float4 item-groups per row
#define NLOG2 0.69314718055994530942f

__device__ __forceinline__ float log1mexp_f(float x) {
    // log(1 - exp(x)) for x <= 0, matching reference branch structure (precise ocml)
    return (x > -NLOG2) ? logf(-expm1f(x)) : log1pf(-expf(x));
}

// Scan output p: module-allocated, disjoint from scan's load streams and from out.
__device__ float g_P[(size_t)NB * NI];

// ---------------- Kernel 1: prep + pack-transpose (verified R3/R5/R8/R10, unchanged) ---
#define TB 64   // rows per tile
#define TK 16   // float4-groups per tile (64 items)
__global__ __launch_bounds__(256) void prep_kernel(const float* __restrict__ logits,
                                                   float* __restrict__ Alp,   // ws: lp_p
                                                   float* __restrict__ Blq) { // out: lq_p
    __shared__ float4 lp_t[TB][TK + 1];
    __shared__ float4 lq_t[TB][TK + 1];
    int bx = blockIdx.x;
    int tb = (bx & 7) * TB;        // row-tile base (512/64 = 8 tiles)
    int tkb = (bx >> 3) * TK;      // group-tile base (2048/16 = 128 tiles)
    int t = threadIdx.x;

    int kl = t & 15;
    int rl0 = t >> 4;  // 0..15
#pragma unroll
    for (int r = 0; r < 4; ++r) {
        int row_local = r * 16 + rl0;
        float4 x4 = *(const float4*)&logits[(size_t)(tb + row_local) * NI + (size_t)(tkb + kl) * 4];
        float4 lp4, lq4;
        const float* xs = &x4.x;
        float* lps = &lp4.x;
        float* lqs = &lq4.x;
#pragma unroll
        for (int j = 0; j < 4; ++j) {
            float x = xs[j];
            float lp = -(fmaxf(-x, 0.0f) + log1pf(expf(-fabsf(x))));
            lp = fminf(lp, -1e-7f);
            lps[j] = lp;
            lqs[j] = log1mexp_f(lp);
        }
        lp_t[row_local][kl] = lp4;
        lq_t[row_local][kl] = lq4;
    }
    __syncthreads();

    int bl = t & 63;
    int kw0 = t >> 6;  // 0..3
#pragma unroll
    for (int w = 0; w < 4; ++w) {
        int k_local = w * 4 + kw0;
        size_t dst = (size_t)(tkb + k_local) * NB + (size_t)(tb + bl);
        ((float4*)Alp)[dst] = lp_t[bl][k_local];
        ((float4*)Blq)[dst] = lq_t[bl][k_local];
    }
}

// ---------------- Kernel 2: scan with LDS-DMA staging (counted vmcnt) ----------
// global_load_lds consumes no VGPRs -> the allocator cannot collapse this pipeline
// (the failure mode of R3/R5/R8/R10, all of which sank register loads to uses).
// Triple-buffered LDS chunk slots, prefetch distance 2 chunks; counted s_waitcnt
// vmcnt(48) per chunk (never 0): newest 48 = 32 just-issued prefetch + 16 stores,
// so it drains exactly the next chunk's staged loads. 2 rows/lane interleaved for
// chain ILP (memory stalls no longer block the wave at load-use points).
// Per-row fp op sequence identical to verified R5/R8/R10 scan_step_p -> bit-exact.
__device__ __forceinline__ void scan_step_p(float lp, float lq, float& S0, float& S1,
                                            float& po) {
    const float L2E = 1.44269504088896340736f;   // log2(e)
    const float LN2 = 0.69314718055994530942f;   // ln(2)
    float x1 = S0 + lp;
    float x2 = S1 + lq;
    float d  = x1 - x2;                          // never NaN (x1 finite)
    float m  = fmaxf(x1, x2);
    float z  = fabsf(d) * -L2E;
    float e  = __builtin_amdgcn_exp2f(z);        // exp2(-inf)=0 handles S1=-inf start
    float a  = 1.0f + e;
    float l  = __builtin_amdgcn_logf(a);
    S1 = fmaf(l, LN2, m);
    S0 = S0 + lq;
    po = fminf(x1 - S1, 0.0f);                   // decide's p, same op order as before
}

#define CH 8      // float4-groups per chunk (32 items per row)
#define SLOTS 3   // triple buffer

#define GLOAD_LDS(gp, lp) \
    __builtin_amdgcn_global_load_lds( \
        (const __attribute__((address_space(1))) void*)(gp), \
        (__attribute__((address_space(3))) void*)(lp), 16, 0, 0)

__global__ __launch_bounds__(64, 1) void scan_kernel(const float* __restrict__ A,
                                                     const float* __restrict__ B) {
    int lane = threadIdx.x;
    int row0 = blockIdx.x * 64 + lane;   // 4 blocks x 64 lanes -> rows [0,256)
    int row1 = row0 + 256;
    const float4* Ap = (const float4*)A;  // float4 index: g*NB + row
    const float4* Bp = (const float4*)B;
    float4* Pp = (float4*)g_P;

    __shared__ float4 sA0[SLOTS][CH][64];  // 24 KB each; 4 arrays = 96 KB
    __shared__ float4 sB0[SLOTS][CH][64];
    __shared__ float4 sA1[SLOTS][CH][64];
    __shared__ float4 sB1[SLOTS][CH][64];

    float S0a = 0.0f, S1a = -INFINITY;
    float S0b = 0.0f, S1b = -INFINITY;

    // prologue: stage chunks 0 and 1 (slots 0, 1); drain chunk 0 (wait leaves 32 = chunk 1)
#pragma unroll
    for (int j = 0; j < CH; ++j) {
        GLOAD_LDS(&Ap[(size_t)(0 * CH + j) * NB + row0], &sA0[0][j][0]);
        GLOAD_LDS(&Bp[(size_t)(0 * CH + j) * NB + row0], &sB0[0][j][0]);
        GLOAD_LDS(&Ap[(size_t)(0 * CH + j) * NB + row1], &sA1[0][j][0]);
        GLOAD_LDS(&Bp[(size_t)(0 * CH + j) * NB + row1], &sB1[0][j][0]);
    }
#pragma unroll
    for (int j = 0; j < CH; ++j) {
        GLOAD_LDS(&Ap[(size_t)(1 * CH + j) * NB + row0], &sA0[1][j][0]);
        GLOAD_LDS(&Bp[(size_t)(1 * CH + j) * NB + row0], &sB0[1][j][0]);
        GLOAD_LDS(&Ap[(size_t)(1 * CH + j) * NB + row1], &sA1[1][j][0]);
        GLOAD_LDS(&Bp[(size_t)(1 * CH + j) * NB + row1], &sB1[1][j][0]);
    }
    asm volatile("s_waitcnt vmcnt(32)" ::: "memory");
    __builtin_amdgcn_sched_barrier(0);

    const int NCHUNK = NG / CH;  // 256
    int s = 0;                   // slot of chunk c
    for (int c = 0; c < NCHUNK; ++c) {
        // issue prefetch for chunk c+2 into slot (s+2)%3 (wrap keeps counts uniform)
        int sn = (s >= 1) ? (s - 1) : (s + 2);   // (s+2)%3
        int cn = (c + 2) & (NCHUNK - 1);
#pragma unroll
        for (int j = 0; j < CH; ++j) {
            GLOAD_LDS(&Ap[(size_t)(cn * CH + j) * NB + row0], &sA0[sn][j][0]);
            GLOAD_LDS(&Bp[(size_t)(cn * CH + j) * NB + row0], &sB0[sn][j][0]);
            GLOAD_LDS(&Ap[(size_t)(cn * CH + j) * NB + row1], &sA1[sn][j][0]);
            GLOAD_LDS(&Bp[(size_t)(cn * CH + j) * NB + row1], &sB1[sn][j][0]);
        }
        // consume chunk c from slot s (ds_read_b128; lgkmcnt handled by compiler)
#pragma unroll
        for (int j = 0; j < CH; ++j) {
            float4 lp0 = sA0[s][j][lane];
            float4 lq0 = sB0[s][j][lane];
            float4 lp1 = sA1[s][j][lane];
            float4 lq1 = sB1[s][j][lane];
            float4 p0, p1;
            scan_step_p(lp0.x, lq0.x, S0a, S1a, p0.x);
            scan_step_p(lp1.x, lq1.x, S0b, S1b, p1.x);
            scan_step_p(lp0.y, lq0.y, S0a, S1a, p0.y);
            scan_step_p(lp1.y, lq1.y, S0b, S1b, p1.y);
            scan_step_p(lp0.z, lq0.z, S0a, S1a, p0.z);
            scan_step_p(lp1.z, lq1.z, S0b, S1b, p1.z);
            scan_step_p(lp0.w, lq0.w, S0a, S1a, p0.w);
            scan_step_p(lp1.w, lq1.w, S0b, S1b, p1.w);
            Pp[(size_t)(c * CH + j) * NB + row0] = p0;
            Pp[(size_t)(c * CH + j) * NB + row1] = p1;
        }
        // counted wait: newest 48 = 32 prefetch (c+2) + 16 stores (c); drains c+1's loads
        asm volatile("s_waitcnt vmcnt(48)" ::: "memory");
        __builtin_amdgcn_sched_barrier(0);
        s = (s >= 2) ? 0 : (s + 1);
    }
}

// ---------------- Kernel 3: decide + one-hot write (verified R8/R10, unchanged) --------
__global__ __launch_bounds__(256) void decide_kernel(const float* __restrict__ noise,
                                                     float* __restrict__ out) {
    int row = blockIdx.x;
    const float4* pp = (const float4*)g_P;
    const float4* ur = (const float4*)(noise + (size_t)row * NI);
    float4* outr = (float4*)(out + (size_t)row * NI);
    int tid = threadIdx.x;

    int best = -1;
#pragma unroll
    for (int k = 0; k < NG / 256; ++k) {  // 8
        int g = tid + k * 256;
        float4 p4 = pp[(size_t)g * NB + row];
        float4 u = ur[g];
#pragma unroll
        for (int j = 0; j < 4; ++j) {
            float p = (&p4.x)[j];
            float q = log1mexp_f(p);            // p==0 -> -inf -> prob 1
            float z = p - q;
            float prob = 1.0f / (1.0f + expf(-z));
            if ((&u.x)[j] < prob) {
                int i = 4 * g + j;
                best = (i > best) ? i : best;
            }
        }
    }

#pragma unroll
    for (int off = 32; off > 0; off >>= 1) {
        int o = __shfl_down(best, off);
        best = (o > best) ? o : best;
    }
    __shared__ int lds[4];
    __shared__ int sel_s;
    int wid = tid >> 6;
    if ((tid & 63) == 0) lds[wid] = best;
    __syncthreads();
    if (tid == 0) {
        int s01 = (lds[0] > lds[1]) ? lds[0] : lds[1];
        int s23 = (lds[2] > lds[3]) ? lds[2] : lds[3];
        sel_s = (s01 > s23) ? s01 : s23;
    }
    __syncthreads();
    int sel = sel_s;

#pragma unroll
    for (int k = 0; k < NG / 256; ++k) {
        int g = tid + k * 256;
        int i0 = 4 * g;
        float4 v;
        v.x = (i0 == sel) ? 1.0f : 0.0f;
        v.y = (i0 + 1 == sel) ? 1.0f : 0.0f;
        v.z = (i0 + 2 == sel) ? 1.0f : 0.0f;
        v.w = (i0 + 3 == sel) ? 1.0f : 0.0f;
        outr[g] = v;
    }
}

extern "C" void kernel_launch(void* const* d_in, const int* in_sizes, int n_in,
                              void* d_out, int out_size, void* d_ws, size_t ws_size,
                              hipStream_t stream) {
    (void)in_sizes; (void)n_in; (void)out_size; (void)ws_size;
    const float* logits = (const float*)d_in[0];
    const float* noise = (const float*)d_in[1];
    float* out = (float*)d_out;       // lq_p -> final 0/1 output (16 MB)
    float* A = (float*)d_ws;          // lp_p (16 MB of ws)

    prep_kernel<<<8 * (NG / TK), 256, 0, stream>>>(logits, A, out);  // 1024 blocks
    scan_kernel<<<4, 64, 0, stream>>>(A, out);   // 256 lanes x 2 rows, LDS-staged
    decide_kernel<<<NB, 256, 0, stream>>>(noise, out);
}